// Round 8
// baseline (580.586 us; speedup 1.0000x reference)
//
#include <hip/hip_runtime.h>
#include <stdint.h>

#define N_NODES 100000
#define N_EDGES 1600000
#define D 128
#define ROWS_PAD 100096   // 782 * 128

typedef long long i64;
typedef __attribute__((ext_vector_type(8))) short bf16x8;
typedef __attribute__((ext_vector_type(4))) float f32x4;
typedef __attribute__((ext_vector_type(4))) float fv4;            // native vecs for nontemporal builtins
typedef __attribute__((ext_vector_type(4))) unsigned short usv4;

// f32 -> bf16 round-to-nearest-even (finite inputs)
__device__ __forceinline__ unsigned short f2bf(float f) {
    union { float f; unsigned u; } v; v.f = f;
    unsigned r = v.u + 0x7fff + ((v.u >> 16) & 1);
    return (unsigned short)(r >> 16);
}
__device__ __forceinline__ float bf2f(unsigned short h) {
    union { unsigned u; float f; } v; v.u = ((unsigned)h) << 16;
    return v.f;
}

// ===========================================================================
// CSR build (proven R2..R7); fill now records the inverse permutation epos[e].
// ===========================================================================
#define SCAN_CHUNK 1024
#define SCAN_THREADS 256
#define N_CHUNKS ((N_NODES + SCAN_CHUNK - 1) / SCAN_CHUNK)   // 98

__global__ __launch_bounds__(256) void count_zero_kernel(int* __restrict__ counts)
{
    const int i = blockIdx.x * 256 + threadIdx.x;
    if (i < N_NODES) counts[i] = 0;
}

__global__ __launch_bounds__(256) void hist_kernel(
    const int* __restrict__ dst, int* __restrict__ counts)
{
    const int e = blockIdx.x * 256 + threadIdx.x;
    if (e < N_EDGES) atomicAdd(&counts[dst[e]], 1);
}

__global__ __launch_bounds__(SCAN_THREADS) void scan_pass1(
    const int* __restrict__ counts, int* __restrict__ blockSums)
{
    __shared__ int sdata[SCAN_THREADS];
    const int b = blockIdx.x, t = threadIdx.x;
    const int base = b * SCAN_CHUNK + t * 4;
    int s = 0;
    #pragma unroll
    for (int k = 0; k < 4; ++k) {
        const int i = base + k;
        if (i < N_NODES) s += counts[i];
    }
    sdata[t] = s; __syncthreads();
    for (int off = SCAN_THREADS / 2; off > 0; off >>= 1) {
        if (t < off) sdata[t] += sdata[t + off];
        __syncthreads();
    }
    if (t == 0) blockSums[b] = sdata[0];
}

__global__ __launch_bounds__(128) void scan_pass2(
    int* __restrict__ blockSums, int* __restrict__ offsets)
{
    __shared__ int sh[128];
    const int t = threadIdx.x;
    const int v = (t < N_CHUNKS) ? blockSums[t] : 0;
    sh[t] = v; __syncthreads();
    for (int off = 1; off < 128; off <<= 1) {
        const int add = (t >= off) ? sh[t - off] : 0;
        __syncthreads();
        sh[t] += add;
        __syncthreads();
    }
    const int incl = sh[t];
    if (t < N_CHUNKS) blockSums[t] = incl - v;       // exclusive chunk base
    if (t == N_CHUNKS - 1) offsets[N_NODES] = incl;  // total = N_EDGES
}

__global__ __launch_bounds__(SCAN_THREADS) void scan_pass3(
    const int* __restrict__ counts, const int* __restrict__ blockSums,
    int* __restrict__ offsets, int* __restrict__ cursor)
{
    __shared__ int sh[SCAN_THREADS];
    const int b = blockIdx.x, t = threadIdx.x;
    const int base = b * SCAN_CHUNK + t * 4;
    int v[4]; int s = 0;
    #pragma unroll
    for (int k = 0; k < 4; ++k) {
        const int i = base + k;
        v[k] = (i < N_NODES) ? counts[i] : 0;
        s += v[k];
    }
    sh[t] = s; __syncthreads();
    for (int off = 1; off < SCAN_THREADS; off <<= 1) {
        const int add = (t >= off) ? sh[t - off] : 0;
        __syncthreads();
        sh[t] += add;
        __syncthreads();
    }
    int run = blockSums[b] + (sh[t] - s);
    #pragma unroll
    for (int k = 0; k < 4; ++k) {
        const int i = base + k;
        if (i < N_NODES) { offsets[i] = run; cursor[i] = run; }
        run += v[k];
    }
}

__global__ __launch_bounds__(256) void fill_pos_kernel(
    const int* __restrict__ dst, int* __restrict__ cursor, int* __restrict__ epos)
{
    const int e = blockIdx.x * 256 + threadIdx.x;
    if (e < N_EDGES) {
        epos[e] = atomicAdd(&cursor[dst[e]], 1);
    }
}

// ===========================================================================
// Zero pad rows of h0 (f32) and h1 (bf16) every call.
// ===========================================================================
__global__ __launch_bounds__(256) void pad_zero_kernel(
    float* __restrict__ h0, unsigned short* __restrict__ h1)
{
    const int i = blockIdx.x * 256 + threadIdx.x;
    const int PADE = (ROWS_PAD - N_NODES) * D;     // 12288
    if (i < PADE) {
        h0[(i64)N_NODES * D + i] = 0.0f;
        h1[(i64)N_NODES * D + i] = 0;
    }
}

// ===========================================================================
// Phase A (edge-major): msgbuf[epos[e]] = bf16(relu(x[src[e]] + ea[e])).
// ea read SEQUENTIALLY (nt), x random but L3-resident, msg 256B random write
// (full-line bf16 rows, fire-and-forget). Half-wave per edge, 8 edges/wave.
// ===========================================================================
__global__ __launch_bounds__(256) void msg_kernel(
    const float* __restrict__ x,
    const int*   __restrict__ srcIdx,
    const float* __restrict__ ea,
    const int*   __restrict__ epos,
    unsigned short* __restrict__ msgbuf)
{
    const int wave = threadIdx.x >> 6;
    const int lane = threadIdx.x & 63;
    const int half = lane >> 5;
    const int c4   = (lane & 31) * 4;   // 4 cols per lane
    const i64 e0 = (i64)blockIdx.x * 32 + wave * 8;   // 8 edges per wave

    #pragma unroll
    for (int k = 0; k < 8; k += 2) {
        const i64 e = e0 + k + half;
        const int s   = srcIdx[e];
        const int pos = epos[e];
        const fv4 xv = *reinterpret_cast<const fv4*>(x + (i64)s * D + c4);
        const fv4 ev = __builtin_nontemporal_load(
            reinterpret_cast<const fv4*>(ea + e * D + c4));
        usv4 m;
        m.x = f2bf(fmaxf(xv.x + ev.x, 0.f));
        m.y = f2bf(fmaxf(xv.y + ev.y, 0.f));
        m.z = f2bf(fmaxf(xv.z + ev.z, 0.f));
        m.w = f2bf(fmaxf(xv.w + ev.w, 0.f));
        __builtin_nontemporal_store(m,
            reinterpret_cast<usv4*>(msgbuf + (i64)pos * D + c4));
    }
}

// ===========================================================================
// Phase B (node-major): h0[v] = x[v] + sum_{p in [p0,p1)} msg[p].
// msgbuf is read front-to-back SEQUENTIALLY (segments are contiguous and in
// node order). Wave per node, lane = 2 cols. Deterministic given msgbuf.
// ===========================================================================
__global__ __launch_bounds__(256) void segsum_kernel(
    const float* __restrict__ x,
    const unsigned short* __restrict__ msgbuf,
    const int* __restrict__ offsets,
    float* __restrict__ h0)
{
    const int wave = threadIdx.x >> 6;
    const int lane = threadIdx.x & 63;
    const int node = blockIdx.x * 4 + wave;
    if (node >= N_NODES) return;
    const int c2 = lane * 2;

    const int p0 = offsets[node];
    const int p1 = offsets[node + 1];

    const float2 xv = *reinterpret_cast<const float2*>(x + (i64)node * D + c2);
    float a0 = xv.x, a1 = xv.y;

    int p = p0;
    for (; p + 3 < p1; p += 4) {
        const ushort2 m0 = *reinterpret_cast<const ushort2*>(msgbuf + (i64)(p + 0) * D + c2);
        const ushort2 m1 = *reinterpret_cast<const ushort2*>(msgbuf + (i64)(p + 1) * D + c2);
        const ushort2 m2 = *reinterpret_cast<const ushort2*>(msgbuf + (i64)(p + 2) * D + c2);
        const ushort2 m3 = *reinterpret_cast<const ushort2*>(msgbuf + (i64)(p + 3) * D + c2);
        a0 += bf2f(m0.x); a1 += bf2f(m0.y);
        a0 += bf2f(m1.x); a1 += bf2f(m1.y);
        a0 += bf2f(m2.x); a1 += bf2f(m2.y);
        a0 += bf2f(m3.x); a1 += bf2f(m3.y);
    }
    for (; p < p1; ++p) {
        const ushort2 m0 = *reinterpret_cast<const ushort2*>(msgbuf + (i64)p * D + c2);
        a0 += bf2f(m0.x); a1 += bf2f(m0.y);
    }

    float2 o; o.x = a0; o.y = a1;
    *reinterpret_cast<float2*>(h0 + (i64)node * D + c2) = o;
}

// ===========================================================================
// MFMA MLP layers (unchanged, proven R5/R7). 16x16x32 bf16 maps:
//   A: row = lane&15, k = 8*(lane>>4)+j ; B: col = lane&15, same k-map
//   C: col = lane&15, row = (lane>>4)*4 + reg
// ===========================================================================
__global__ __launch_bounds__(256) void mlp1_mfma_kernel(
    const float* __restrict__ hin,            // [ROWS_PAD][D] f32
    const float* __restrict__ w,              // [D][D] f32, w[k*D+col]
    const float* __restrict__ bias,           // [D]
    unsigned short* __restrict__ hout)        // [ROWS_PAD][D] bf16
{
    const int tid  = threadIdx.x;
    const int wave = tid >> 6;
    const int lane = tid & 63;
    const int g    = lane >> 4;
    const int lr   = lane & 15;
    const int colbase = wave * 32;

    bf16x8 bfrag[4][2];
    #pragma unroll
    for (int ks = 0; ks < 4; ++ks) {
        #pragma unroll
        for (int nt = 0; nt < 2; ++nt) {
            const int col = colbase + nt * 16 + lr;
            const int k0  = ks * 32 + g * 8;
            bf16x8 f;
            #pragma unroll
            for (int j = 0; j < 8; ++j)
                f[j] = (short)f2bf(w[(k0 + j) * D + col]);
            bfrag[ks][nt] = f;
        }
    }
    const float bc0 = bias[colbase + lr];
    const float bc1 = bias[colbase + 16 + lr];

    const int rowbase0 = blockIdx.x * 128;
    #pragma unroll 1
    for (int sub = 0; sub < 8; ++sub) {
        const int rowbase = rowbase0 + sub * 16;
        const int arow = rowbase + lr;

        bf16x8 afrag[4];
        #pragma unroll
        for (int ks = 0; ks < 4; ++ks) {
            const float* ap = hin + (i64)arow * D + ks * 32 + g * 8;
            const float4 u0 = *reinterpret_cast<const float4*>(ap);
            const float4 u1 = *reinterpret_cast<const float4*>(ap + 4);
            bf16x8 f;
            f[0] = (short)f2bf(u0.x); f[1] = (short)f2bf(u0.y);
            f[2] = (short)f2bf(u0.z); f[3] = (short)f2bf(u0.w);
            f[4] = (short)f2bf(u1.x); f[5] = (short)f2bf(u1.y);
            f[6] = (short)f2bf(u1.z); f[7] = (short)f2bf(u1.w);
            afrag[ks] = f;
        }

        f32x4 acc0 = { bc0, bc0, bc0, bc0 };
        f32x4 acc1 = { bc1, bc1, bc1, bc1 };
        #pragma unroll
        for (int ks = 0; ks < 4; ++ks) {
            acc0 = __builtin_amdgcn_mfma_f32_16x16x32_bf16(afrag[ks], bfrag[ks][0], acc0, 0, 0, 0);
            acc1 = __builtin_amdgcn_mfma_f32_16x16x32_bf16(afrag[ks], bfrag[ks][1], acc1, 0, 0, 0);
        }

        #pragma unroll
        for (int r = 0; r < 4; ++r) {
            const int orow = rowbase + g * 4 + r;
            hout[(i64)orow * D + colbase + lr]      = f2bf(fmaxf(acc0[r], 0.f));
            hout[(i64)orow * D + colbase + 16 + lr] = f2bf(fmaxf(acc1[r], 0.f));
        }
    }
}

__global__ __launch_bounds__(256) void mlp2_mfma_kernel(
    const unsigned short* __restrict__ hin,   // [ROWS_PAD][D] bf16
    const float* __restrict__ w,
    const float* __restrict__ bias,
    float* __restrict__ hout)                 // [N_NODES][D] f32
{
    const int tid  = threadIdx.x;
    const int wave = tid >> 6;
    const int lane = tid & 63;
    const int g    = lane >> 4;
    const int lr   = lane & 15;
    const int colbase = wave * 32;

    bf16x8 bfrag[4][2];
    #pragma unroll
    for (int ks = 0; ks < 4; ++ks) {
        #pragma unroll
        for (int nt = 0; nt < 2; ++nt) {
            const int col = colbase + nt * 16 + lr;
            const int k0  = ks * 32 + g * 8;
            bf16x8 f;
            #pragma unroll
            for (int j = 0; j < 8; ++j)
                f[j] = (short)f2bf(w[(k0 + j) * D + col]);
            bfrag[ks][nt] = f;
        }
    }
    const float bc0 = bias[colbase + lr];
    const float bc1 = bias[colbase + 16 + lr];

    const int rowbase0 = blockIdx.x * 128;
    #pragma unroll 1
    for (int sub = 0; sub < 8; ++sub) {
        const int rowbase = rowbase0 + sub * 16;
        const int arow = rowbase + lr;

        bf16x8 afrag[4];
        #pragma unroll
        for (int ks = 0; ks < 4; ++ks)
            afrag[ks] = *reinterpret_cast<const bf16x8*>(
                hin + (i64)arow * D + ks * 32 + g * 8);

        f32x4 acc0 = { bc0, bc0, bc0, bc0 };
        f32x4 acc1 = { bc1, bc1, bc1, bc1 };
        #pragma unroll
        for (int ks = 0; ks < 4; ++ks) {
            acc0 = __builtin_amdgcn_mfma_f32_16x16x32_bf16(afrag[ks], bfrag[ks][0], acc0, 0, 0, 0);
            acc1 = __builtin_amdgcn_mfma_f32_16x16x32_bf16(afrag[ks], bfrag[ks][1], acc1, 0, 0, 0);
        }

        #pragma unroll
        for (int r = 0; r < 4; ++r) {
            const int orow = rowbase + g * 4 + r;
            if (orow < N_NODES) {
                hout[(i64)orow * D + colbase + lr]      = acc0[r];
                hout[(i64)orow * D + colbase + 16 + lr] = acc1[r];
            }
        }
    }
}

// ===========================================================================
// Fallback path (R2-proven) — only if ws too small
// ===========================================================================
__global__ __launch_bounds__(256) void init_acc_kernel(
    const float* __restrict__ x, float* __restrict__ acc)
{
    const int i = blockIdx.x * blockDim.x + threadIdx.x;
    const int n = N_NODES * D / 4;
    if (i < n)
        reinterpret_cast<float4*>(acc)[i] = reinterpret_cast<const float4*>(x)[i];
}

__global__ __launch_bounds__(256) void edge_scatter_kernel(
    const float* __restrict__ x,
    const int*  __restrict__ src,
    const int*  __restrict__ dst,
    const float* __restrict__ ea,
    float* __restrict__ acc)
{
    const int lane = threadIdx.x & 31;
    const int grp  = threadIdx.x >> 5;
    const i64 e = (i64)blockIdx.x * 8 + grp;
    if (e >= N_EDGES) return;
    const int s = src[e];
    const int d = dst[e];
    const int j = lane * 4;
    const float4 xv = *reinterpret_cast<const float4*>(x  + (i64)s * D + j);
    const float4 ev = *reinterpret_cast<const float4*>(ea + e * D + j);
    float4 m;
    m.x = fmaxf(xv.x + ev.x, 0.0f);
    m.y = fmaxf(xv.y + ev.y, 0.0f);
    m.z = fmaxf(xv.z + ev.z, 0.0f);
    m.w = fmaxf(xv.w + ev.w, 0.0f);
    float* pp = acc + (i64)d * D + j;
    atomicAdd(pp + 0, m.x);
    atomicAdd(pp + 1, m.y);
    atomicAdd(pp + 2, m.z);
    atomicAdd(pp + 3, m.w);
}

#define MLP_THREADS 512
#define ROWS_PER_CHUNK 16
#define CHUNKS_PER_BLOCK 4
#define ROWS_PER_BLOCK (ROWS_PER_CHUNK * CHUNKS_PER_BLOCK)

template<bool RELU>
__global__ __launch_bounds__(MLP_THREADS) void mlp_layer_kernel(
    const float* __restrict__ hin,
    const float* __restrict__ w,
    const float* __restrict__ b,
    float* __restrict__ hout)
{
    __shared__ float ws_[D * D];
    __shared__ float bs_[D];
    __shared__ float hrow[ROWS_PER_CHUNK][D];

    const int tid = threadIdx.x;
    for (int t = tid; t < D * D / 4; t += MLP_THREADS)
        reinterpret_cast<float4*>(ws_)[t] = reinterpret_cast<const float4*>(w)[t];
    if (tid < D) bs_[tid] = b[tid];

    const int j = tid & (D - 1);
    const int q = tid >> 7;
    const int rowBase = blockIdx.x * ROWS_PER_BLOCK;

    for (int c = 0; c < CHUNKS_PER_BLOCK; ++c) {
        const int chunkRow = rowBase + c * ROWS_PER_CHUNK;
        __syncthreads();
        {
            const int r   = tid >> 5;
            const int col = (tid & 31) * 4;
            const int gi  = chunkRow + r;
            float4 v = make_float4(0.f, 0.f, 0.f, 0.f);
            if (gi < N_NODES)
                v = *reinterpret_cast<const float4*>(hin + (i64)gi * D + col);
            *reinterpret_cast<float4*>(&hrow[r][col]) = v;
        }
        __syncthreads();

        float acc0 = bs_[j], acc1 = bs_[j], acc2 = bs_[j], acc3 = bs_[j];
        const int r0 = q * 4;
        #pragma unroll 4
        for (int k = 0; k < D; ++k) {
            const float wv = ws_[k * D + j];
            acc0 = fmaf(hrow[r0 + 0][k], wv, acc0);
            acc1 = fmaf(hrow[r0 + 1][k], wv, acc1);
            acc2 = fmaf(hrow[r0 + 2][k], wv, acc2);
            acc3 = fmaf(hrow[r0 + 3][k], wv, acc3);
        }
        if (RELU) {
            acc0 = fmaxf(acc0, 0.f); acc1 = fmaxf(acc1, 0.f);
            acc2 = fmaxf(acc2, 0.f); acc3 = fmaxf(acc3, 0.f);
        }
        const int gi = chunkRow + r0;
        if (gi + 0 < N_NODES) hout[(i64)(gi + 0) * D + j] = acc0;
        if (gi + 1 < N_NODES) hout[(i64)(gi + 1) * D + j] = acc1;
        if (gi + 2 < N_NODES) hout[(i64)(gi + 2) * D + j] = acc2;
        if (gi + 3 < N_NODES) hout[(i64)(gi + 3) * D + j] = acc3;
    }
}

// ===========================================================================
extern "C" void kernel_launch(void* const* d_in, const int* in_sizes, int n_in,
                              void* d_out, int out_size, void* d_ws, size_t ws_size,
                              hipStream_t stream)
{
    const float* x  = (const float*)d_in[0];
    const int*   ei = (const int*)  d_in[1];   // [2, E] int32
    const float* ea = (const float*)d_in[2];
    const float* w1 = (const float*)d_in[3];
    const float* b1 = (const float*)d_in[4];
    const float* w2 = (const float*)d_in[5];
    const float* b2 = (const float*)d_in[6];
    float* out = (float*)d_out;

    const int* src = ei;
    const int* dst = ei + N_EDGES;

    // ws layout: ints (counts|offsets|cursor|blockSums|epos) | h0 f32 | h1 bf16 | msgbuf bf16[E][D]
    const size_t INT_REGION = (size_t)N_NODES + (N_NODES + 1) + N_NODES + 128 + N_EDGES;
    const size_t H_ELEMS    = (size_t)ROWS_PAD * D;
    const size_t MSG_ELEMS  = (size_t)N_EDGES * D;
    const size_t WS_NEEDED  = INT_REGION * 4 + 128 + H_ELEMS * 4 + H_ELEMS * 2 + MSG_ELEMS * 2;

    if (ws_size >= WS_NEEDED) {
        int* counts    = (int*)d_ws;
        int* offsets   = counts + N_NODES;
        int* cursor    = offsets + (N_NODES + 1);
        int* blockSums = cursor + N_NODES;
        int* epos      = blockSums + 128;
        uintptr_t p = (uintptr_t)(epos + N_EDGES);
        p = (p + 63) & ~(uintptr_t)63;
        float* h0 = (float*)p;
        unsigned short* h1 = (unsigned short*)(h0 + H_ELEMS);
        unsigned short* msgbuf = h1 + H_ELEMS;

        count_zero_kernel<<<(N_NODES + 255) / 256, 256, 0, stream>>>(counts);
        hist_kernel<<<(N_EDGES + 255) / 256, 256, 0, stream>>>(dst, counts);
        scan_pass1<<<N_CHUNKS, SCAN_THREADS, 0, stream>>>(counts, blockSums);
        scan_pass2<<<1, 128, 0, stream>>>(blockSums, offsets);
        scan_pass3<<<N_CHUNKS, SCAN_THREADS, 0, stream>>>(counts, blockSums, offsets, cursor);
        fill_pos_kernel<<<(N_EDGES + 255) / 256, 256, 0, stream>>>(dst, cursor, epos);
        pad_zero_kernel<<<48, 256, 0, stream>>>(h0, h1);

        // Phase A: edge-major message build (8 edges per wave, 32 per block)
        msg_kernel<<<N_EDGES / 32, 256, 0, stream>>>(x, src, ea, epos, msgbuf);
        // Phase B: sequential segmented sum
        segsum_kernel<<<(N_NODES + 3) / 4, 256, 0, stream>>>(x, msgbuf, offsets, h0);

        const int mlpBlocks = ROWS_PAD / 128;   // 782
        mlp1_mfma_kernel<<<mlpBlocks, 256, 0, stream>>>(h0, w1, b1, h1);
        mlp2_mfma_kernel<<<mlpBlocks, 256, 0, stream>>>(h1, w2, b2, out);
    } else {
        const int n = N_NODES * D / 4;
        init_acc_kernel<<<(n + 255) / 256, 256, 0, stream>>>(x, out);
        edge_scatter_kernel<<<(N_EDGES + 7) / 8, 256, 0, stream>>>(x, src, dst, ea, out);
        const int blocks = (N_NODES + ROWS_PER_BLOCK - 1) / ROWS_PER_BLOCK;
        mlp_layer_kernel<true ><<<blocks, MLP_THREADS, 0, stream>>>(out, w1, b1, out);
        mlp_layer_kernel<false><<<blocks, MLP_THREADS, 0, stream>>>(out, w2, b2, out);
    }
}